// Round 10
// baseline (237.215 us; speedup 1.0000x reference)
//
#include <hip/hip_runtime.h>
#include <hip/hip_bf16.h>
#include <math.h>

#define BB 8
#define CCH 256          // channels
#define NN 2304          // H*W
#define NH 4
#define HDIM 64
#define QKV_ROWS 384
#define BN_EPS 1e-5f
#define NTILES 36        // NN / 64
#define HTILES 18        // NTILES / 2 (key-split halves)
// scale folded into q weights: 1/sqrt(64) * log2(e)  -> attention uses exp2
#define SLOG2E 0.18033688011112042f

typedef short bf16x8 __attribute__((ext_vector_type(8)));
typedef short bf16x4 __attribute__((ext_vector_type(4)));
typedef float f32x4 __attribute__((ext_vector_type(4)));

#if __has_builtin(__builtin_amdgcn_exp2f)
#define EXP2(x) __builtin_amdgcn_exp2f(x)
#else
#define EXP2(x) __expf((x) * 0.6931471805599453f)
#endif

// K=16 bf16 MFMA: A/B = 4 bf16 (2 VGPRs), C/D = 4 f32 (ISA §10).
#define MFMA16(a, b, c) __builtin_amdgcn_mfma_f32_16x16x16bf16_1k(a, b, c, 0, 0, 0)
#define MFMA32(a, b, c) __builtin_amdgcn_mfma_f32_16x16x32_bf16(a, b, c, 0, 0, 0)

__device__ __forceinline__ unsigned bfpair(float a, float b) {
    __hip_bfloat162 h = __float22bfloat162_rn(make_float2(a, b));
    return *(unsigned*)&h;
}
__device__ __forceinline__ unsigned short f2bf(float f) {
    unsigned u = __float_as_uint(f);
    u = (u + 0x7FFFu + ((u >> 16) & 1u)) >> 16;
    return (unsigned short)u;
}
__device__ __forceinline__ bf16x4 pack4(float p0, float p1, float p2, float p3) {
    union { unsigned u[2]; bf16x4 v; } x;
    x.u[0] = bfpair(p0, p1);
    x.u[1] = bfpair(p2, p3);
    return x.v;
}
__device__ __forceinline__ float bf2f(unsigned short s) {
    return __uint_as_float((unsigned)s << 16);
}

// ---------------------------------------------------------------------------
// K0a: x[b][c][n] fp32 -> xT[b][n][c] bf16.  grid (8 b, 36 ntile, 4 ctile)
// ---------------------------------------------------------------------------
__global__ __launch_bounds__(256) void cvt_x_k(
    const float* __restrict__ x, unsigned short* __restrict__ xT)
{
    __shared__ float sX[64][65];
    const int tid = threadIdx.x;
    const int b  = blockIdx.x;
    const int nb = blockIdx.y * 64;
    const int cb = blockIdx.z * 64;

    #pragma unroll
    for (int u = 0; u < 4; ++u) {
        int c  = (tid >> 4) + 16 * u;
        int n4 = (tid & 15) * 4;
        float4 v = *(const float4*)(x + ((size_t)(b * CCH + cb + c)) * NN + nb + n4);
        sX[c][n4+0] = v.x; sX[c][n4+1] = v.y; sX[c][n4+2] = v.z; sX[c][n4+3] = v.w;
    }
    __syncthreads();

    const int n  = tid >> 2;
    const int cg = (tid & 3) * 16;
    unsigned vals[8];
    #pragma unroll
    for (int p = 0; p < 8; ++p)
        vals[p] = bfpair(sX[cg + 2*p][n], sX[cg + 2*p + 1][n]);
    unsigned short* dst = xT + ((size_t)(b * NN + nb + n)) * CCH + cb + cg;
    *(uint4*)dst = make_uint4(vals[0], vals[1], vals[2], vals[3]);
    *(uint4*)(dst + 8) = make_uint4(vals[4], vals[5], vals[6], vals[7]);
}

// ---------------------------------------------------------------------------
// K0b: weights -> bf16. Wb[384][256] = concat(qw*SLOG2E, kw, vw); Pb = pw.
// ---------------------------------------------------------------------------
__global__ __launch_bounds__(256) void cvt_w_k(
    const float* __restrict__ qw, const float* __restrict__ kw,
    const float* __restrict__ vw, const float* __restrict__ pw,
    unsigned short* __restrict__ Wb, unsigned short* __restrict__ Pb)
{
    int idx = blockIdx.x * 256 + threadIdx.x;
    if (idx < 98304) {
        int o = idx >> 8, c = idx & 255;
        float v;
        if (o < 256)      v = qw[(size_t)o * CCH + c] * SLOG2E;
        else if (o < 320) v = kw[(size_t)(o - 256) * CCH + c];
        else              v = vw[(size_t)(o - 320) * CCH + c];
        Wb[idx] = f2bf(v);
    } else {
        int j = idx - 98304;
        if (j < 65536) Pb[j] = f2bf(pw[j]);
    }
}

// ---------------------------------------------------------------------------
// K1: qkv MFMA GEMM, K-loop software-pipelined (double-buffered fragments).
// grid (8 b, 36 ntile, 3 otile), 128 thr (2 waves).
//   Qt[b][n][256] (q pre-scaled), Kt[b][n][64], Vn[b][64][n], all bf16.
// ---------------------------------------------------------------------------
__global__ __launch_bounds__(128) void qkv_mfma_k(
    const unsigned short* __restrict__ Wb, const unsigned short* __restrict__ xT,
    unsigned short* __restrict__ Qt, unsigned short* __restrict__ Kt,
    unsigned short* __restrict__ Vn)
{
    __shared__ unsigned short sE[2][64 * 72];
    const int tid = threadIdx.x;
    const int wave = tid >> 6;
    const int lane = tid & 63;
    const int quad = lane >> 4;
    const int l15  = lane & 15;
    const int b  = blockIdx.x;
    const int nb = blockIdx.y * 64;
    const int mb = blockIdx.z * 128 + wave * 64;

    const unsigned short* Ab = Wb + (size_t)(mb + l15) * CCH + quad * 8;
    const unsigned short* Bb = xT + ((size_t)(b * NN + nb + l15)) * CCH + quad * 8;

    f32x4 C[4][4] = {};
    bf16x8 aA[2][4], bB[2][4];
    #pragma unroll
    for (int i = 0; i < 4; ++i) aA[0][i] = *(const bf16x8*)(Ab + (size_t)(16*i) * CCH);
    #pragma unroll
    for (int j = 0; j < 4; ++j) bB[0][j] = *(const bf16x8*)(Bb + (size_t)(16*j) * CCH);

    #pragma unroll
    for (int kk = 0; kk < 8; ++kk) {
        const int cur = kk & 1;
        if (kk < 7) {
            const int k1 = (kk + 1) * 32;
            #pragma unroll
            for (int i = 0; i < 4; ++i) aA[cur^1][i] = *(const bf16x8*)(Ab + (size_t)(16*i) * CCH + k1);
            #pragma unroll
            for (int j = 0; j < 4; ++j) bB[cur^1][j] = *(const bf16x8*)(Bb + (size_t)(16*j) * CCH + k1);
        }
        #pragma unroll
        for (int i = 0; i < 4; ++i)
            #pragma unroll
            for (int j = 0; j < 4; ++j)
                C[i][j] = MFMA32(aA[cur][i], bB[cur][j], C[i][j]);
    }

    unsigned short* sEw = &sE[wave][0];
    if (mb < 320) {
        // Q or K: transpose to [n][o] rows
        #pragma unroll
        for (int i = 0; i < 4; ++i)
            #pragma unroll
            for (int j = 0; j < 4; ++j) {
                unsigned p01 = bfpair(C[i][j][0], C[i][j][1]);
                unsigned p23 = bfpair(C[i][j][2], C[i][j][3]);
                unsigned short* p = sEw + (16*j + l15) * 72 + 16*i + quad*4;
                *(unsigned*)p = p01;
                *(unsigned*)(p + 2) = p23;
            }
        if (mb < 256) {
            #pragma unroll
            for (int it = 0; it < 8; ++it) {
                int flat = lane + 64 * it;
                int row = flat >> 3;
                int o8  = (flat & 7) * 8;
                uint4 v = *(const uint4*)(sEw + row * 72 + o8);
                *(uint4*)(Qt + ((size_t)(b * NN + nb + row)) * CCH + mb + o8) = v;
            }
        } else {
            #pragma unroll
            for (int it = 0; it < 8; ++it) {
                int flat = lane + 64 * it;
                int row = flat >> 3;
                int o8  = (flat & 7) * 8;
                uint4 v = *(const uint4*)(sEw + row * 72 + o8);
                *(uint4*)(Kt + ((size_t)(b * NN + nb + row)) * 64 + o8) = v;
            }
        }
    } else {
        // V: [d][n] rows
        #pragma unroll
        for (int i = 0; i < 4; ++i)
            #pragma unroll
            for (int j = 0; j < 4; ++j) {
                unsigned p01 = bfpair(C[i][j][0], C[i][j][1]);
                unsigned p23 = bfpair(C[i][j][2], C[i][j][3]);
                unsigned short* p = sEw + (16*i + quad*4) * 72 + 16*j + l15;
                p[0]   = (unsigned short)p01;
                p[72]  = (unsigned short)(p01 >> 16);
                p[144] = (unsigned short)p23;
                p[216] = (unsigned short)(p23 >> 16);
            }
        #pragma unroll
        for (int it = 0; it < 8; ++it) {
            int flat = lane + 64 * it;
            int row = flat >> 3;
            int n8  = (flat & 7) * 8;
            uint4 v = *(const uint4*)(sEw + row * 72 + n8);
            *(uint4*)(Vn + ((size_t)(b * 64 + (mb - 320) + row)) * NN + nb + n8) = v;
        }
    }
}

// ---------------------------------------------------------------------------
// K2: MFMA attention, transposed-S + key-split + register prefetch +
// XOR-swizzled unpadded LDS (32 KB exactly -> 5 blocks/CU vs 4 at pad-72).
// grid (8 b, 36 qtile, 4 head), 256 thr = 4 waves: (qslot) x (khalf).
// LDS chunk swizzle: element addr = row*64 + (chunk ^ (row&7))*8 + sub.
// Lanes sharing a chunk <= 2 -> 2-way bank aliasing (free, m136).
// ---------------------------------------------------------------------------
__global__ __launch_bounds__(256, 5) void attn_k(
    const unsigned short* __restrict__ Qt,  // [B][N][256]
    const unsigned short* __restrict__ Kt,  // [B][N][64]
    const unsigned short* __restrict__ Vn,  // [B][64][N]
    unsigned short* __restrict__ Ao)        // [B][N][256]
{
    // 4 tile buffers: Kh0, Vh0, Kh1, Vh1 — each [64 rows][64] bf16, swizzled
    __shared__ __align__(16) unsigned short sKV[4 * 64 * 64];   // 32768 B

    const int tid   = threadIdx.x;
    const int wave  = tid >> 6;
    const int lane  = tid & 63;
    const int quad  = lane >> 4;
    const int l15   = lane & 15;
    const int qslot = wave & 1;
    const int kh    = wave >> 1;
    const int qoff  = qslot * 32;
    const int b     = blockIdx.x;
    const int nb    = blockIdx.y * 64;
    const int head  = blockIdx.z;

    unsigned short* sKb = sKV + kh * 2 * 4096;
    unsigned short* sVb = sKb + 4096;

    // Q fragments (B-operand for S^T): B[n=query=l15][k=d=quad*8+j]
    bf16x8 bQ[2][2];
    const unsigned short* QtB = Qt + ((size_t)(b * NN + nb + qoff + l15)) * CCH + head * 64 + quad * 8;
    #pragma unroll
    for (int qt = 0; qt < 2; ++qt)
        #pragma unroll
        for (int s = 0; s < 2; ++s)
            bQ[qt][s] = *(const bf16x8*)(QtB + (size_t)(16*qt) * CCH + s * 32);

    // per-thread staging geometry (8 chunks: u>>1 = buffer, key-half = buf>>1)
    // prefetch step 0 into registers
    bf16x8 pf[8];
    #pragma unroll
    for (int u = 0; u < 8; ++u) {
        const int buf   = u >> 1;               // 0:K0 1:V0 2:K1 3:V1
        const int khb   = buf >> 1;
        const int local = (u & 1) * 256 + tid;  // 0..511
        const int row   = local >> 3;
        const int ch8   = (local & 7) * 8;
        const int keys0 = khb * HTILES * 64;
        if ((buf & 1) == 0)
            pf[u] = *(const bf16x8*)(Kt + ((size_t)(b * NN + keys0 + row)) * 64 + ch8);
        else
            pf[u] = *(const bf16x8*)(Vn + ((size_t)(b * 64 + row)) * NN + keys0 + ch8);
    }

    f32x4 O[4][2] = {};          // O^T[d-tile jd][q-tile qt]
    float lacc[2] = {0.f, 0.f};  // per-lane partial denominators (q = l15)

    for (int step = 0; step < HTILES; ++step) {
        __syncthreads();   // all waves done with previous tiles
        #pragma unroll
        for (int u = 0; u < 8; ++u) {
            const int buf   = u >> 1;
            const int local = (u & 1) * 256 + tid;
            const int row   = local >> 3;
            const int chsw  = ((local & 7) ^ (row & 7)) * 8;
            *(bf16x8*)(sKV + buf * 4096 + row * 64 + chsw) = pf[u];
        }
        __syncthreads();

        // prefetch next step during compute
        if (step + 1 < HTILES) {
            #pragma unroll
            for (int u = 0; u < 8; ++u) {
                const int buf   = u >> 1;
                const int khb   = buf >> 1;
                const int local = (u & 1) * 256 + tid;
                const int row   = local >> 3;
                const int ch8   = (local & 7) * 8;
                const int keys0 = (khb * HTILES + step + 1) * 64;
                if ((buf & 1) == 0)
                    pf[u] = *(const bf16x8*)(Kt + ((size_t)(b * NN + keys0 + row)) * 64 + ch8);
                else
                    pf[u] = *(const bf16x8*)(Vn + ((size_t)(b * 64 + row)) * NN + keys0 + ch8);
            }
        }

        // S^T[key][q]: kt = key subtile, qt = query subtile
        f32x4 C[4][2] = {};
        #pragma unroll
        for (int s = 0; s < 2; ++s)
            #pragma unroll
            for (int kt = 0; kt < 4; ++kt) {
                const int row = 16*kt + l15;
                const int chsw = ((s*4 + quad) ^ (row & 7)) * 8;
                bf16x8 aK = *(const bf16x8*)(sKb + row * 64 + chsw);
                C[kt][0] = MFMA32(aK, bQ[0][s], C[kt][0]);
                C[kt][1] = MFMA32(aK, bQ[1][s], C[kt][1]);
            }

        // P^T = exp2(S^T) in regs -> bf16 B-fragments for K=16 MFMA
        bf16x4 bP[4][2];
        #pragma unroll
        for (int kt = 0; kt < 4; ++kt)
            #pragma unroll
            for (int qt = 0; qt < 2; ++qt) {
                float p0 = EXP2(C[kt][qt][0]);
                float p1 = EXP2(C[kt][qt][1]);
                float p2 = EXP2(C[kt][qt][2]);
                float p3 = EXP2(C[kt][qt][3]);
                lacc[qt] += (p0 + p1) + (p2 + p3);
                bP[kt][qt] = pack4(p0, p1, p2, p3);
            }

        // O^T += V . P^T   (A = V[d][key], k = quad*4+j keys)
        #pragma unroll
        for (int jd = 0; jd < 4; ++jd)
            #pragma unroll
            for (int kt = 0; kt < 4; ++kt) {
                const int row = 16*jd + l15;
                const int chsw = ((2*kt + (quad >> 1)) ^ (row & 7)) * 8 + (quad & 1) * 4;
                bf16x4 aV = *(const bf16x4*)(sVb + row * 64 + chsw);
                O[jd][0] = MFMA16(aV, bP[kt][0], O[jd][0]);
                O[jd][1] = MFMA16(aV, bP[kt][1], O[jd][1]);
            }
    }
    __syncthreads();   // all K/V reads done before scratch overlay

    // merge key halves: kh=1 waves dump O + lacc to LDS scratch (floats)
    float* sc = (float*)sKV;                           // 0..18432 B
    unsigned short* sT = (unsigned short*)sKV + 9216;  // 18432..27648 B, [64][72]
    if (kh == 1) {
        const int base = qslot * 2304 + lane * 36;
        #pragma unroll
        for (int jd = 0; jd < 4; ++jd)
            #pragma unroll
            for (int qt = 0; qt < 2; ++qt)
                *(f32x4*)(sc + base + jd * 8 + qt * 4) = O[jd][qt];
        sc[base + 32] = lacc[0];
        sc[base + 33] = lacc[1];
    }
    __syncthreads();
    if (kh == 0) {
        const int base = qslot * 2304 + lane * 36;
        #pragma unroll
        for (int jd = 0; jd < 4; ++jd)
            #pragma unroll
            for (int qt = 0; qt < 2; ++qt)
                O[jd][qt] += *(const f32x4*)(sc + base + jd * 8 + qt * 4);
        lacc[0] += sc[base + 32];
        lacc[1] += sc[base + 33];

        float rinv[2];
        #pragma unroll
        for (int qt = 0; qt < 2; ++qt) {
            float s = lacc[qt];
            s += __shfl_xor(s, 16);
            s += __shfl_xor(s, 32);
            rinv[qt] = 1.0f / s;
        }
        // sT[n_local][d]: n = qoff + 16qt + l15, d = 16jd + quad*4 + r
        #pragma unroll
        for (int qt = 0; qt < 2; ++qt)
            #pragma unroll
            for (int jd = 0; jd < 4; ++jd) {
                unsigned lo = bfpair(O[jd][qt][0] * rinv[qt], O[jd][qt][1] * rinv[qt]);
                unsigned hi = bfpair(O[jd][qt][2] * rinv[qt], O[jd][qt][3] * rinv[qt]);
                *(uint2*)(sT + (qoff + 16*qt + l15) * 72 + 16*jd + quad*4) = make_uint2(lo, hi);
            }
    }
    __syncthreads();

    // coalesced writeout: 64 rows x 64 channels bf16 = 512 uint4 chunks
    #pragma unroll
    for (int it = 0; it < 2; ++it) {
        int flat = tid + 256 * it;          // 0..511
        int row = flat >> 3;
        int c8  = (flat & 7) * 8;
        uint4 v = *(const uint4*)(sT + row * 72 + c8);
        *(uint4*)(Ao + ((size_t)(b * NN + nb + row)) * CCH + head * 64 + c8) = v;
    }
}

// ---------------------------------------------------------------------------
// K3: proj MFMA GEMM, K-loop software-pipelined.
// projb[b][c][n] (bf16) = sum_o Pb[c][o]*Ao[b][n][o]+pb[c]
// grid (8 b, 36 ntile, 2 ctile), 128 thr (2 waves).
// ---------------------------------------------------------------------------
__global__ __launch_bounds__(128) void proj_mfma_k(
    const unsigned short* __restrict__ Pb, const unsigned short* __restrict__ Ao,
    const float* __restrict__ pb, unsigned short* __restrict__ projb)
{
    __shared__ unsigned short sE[2][64 * 72];
    const int tid = threadIdx.x;
    const int wave = tid >> 6;
    const int lane = tid & 63;
    const int quad = lane >> 4;
    const int l15  = lane & 15;
    const int b  = blockIdx.x;
    const int nb = blockIdx.y * 64;
    const int mb = blockIdx.z * 128 + wave * 64;

    const unsigned short* Ab = Pb + (size_t)(mb + l15) * CCH + quad * 8;
    const unsigned short* Bb = Ao + ((size_t)(b * NN + nb + l15)) * CCH + quad * 8;

    f32x4 C[4][4] = {};
    bf16x8 aA[2][4], bB[2][4];
    #pragma unroll
    for (int i = 0; i < 4; ++i) aA[0][i] = *(const bf16x8*)(Ab + (size_t)(16*i) * CCH);
    #pragma unroll
    for (int j = 0; j < 4; ++j) bB[0][j] = *(const bf16x8*)(Bb + (size_t)(16*j) * CCH);

    #pragma unroll
    for (int kk = 0; kk < 8; ++kk) {
        const int cur = kk & 1;
        if (kk < 7) {
            const int k1 = (kk + 1) * 32;
            #pragma unroll
            for (int i = 0; i < 4; ++i) aA[cur^1][i] = *(const bf16x8*)(Ab + (size_t)(16*i) * CCH + k1);
            #pragma unroll
            for (int j = 0; j < 4; ++j) bB[cur^1][j] = *(const bf16x8*)(Bb + (size_t)(16*j) * CCH + k1);
        }
        #pragma unroll
        for (int i = 0; i < 4; ++i)
            #pragma unroll
            for (int j = 0; j < 4; ++j)
                C[i][j] = MFMA32(aA[cur][i], bB[cur][j], C[i][j]);
    }

    unsigned short* sEw = &sE[wave][0];
    #pragma unroll
    for (int i = 0; i < 4; ++i)
        #pragma unroll
        for (int j = 0; j < 4; ++j) {
            const float b0 = pb[mb + 16*i + quad*4 + 0];
            const float b1 = pb[mb + 16*i + quad*4 + 1];
            const float b2 = pb[mb + 16*i + quad*4 + 2];
            const float b3 = pb[mb + 16*i + quad*4 + 3];
            unsigned p01 = bfpair(C[i][j][0] + b0, C[i][j][1] + b1);
            unsigned p23 = bfpair(C[i][j][2] + b2, C[i][j][3] + b3);
            unsigned short* p = sEw + (16*i + quad*4) * 72 + 16*j + l15;
            p[0]   = (unsigned short)p01;
            p[72]  = (unsigned short)(p01 >> 16);
            p[144] = (unsigned short)p23;
            p[216] = (unsigned short)(p23 >> 16);
        }
    #pragma unroll
    for (int it = 0; it < 8; ++it) {
        int flat = lane + 64 * it;
        int row = flat >> 3;                // c local
        int n8  = (flat & 7) * 8;
        uint4 v = *(const uint4*)(sEw + row * 72 + n8);
        *(uint4*)(projb + ((size_t)(b * CCH + mb + row)) * NN + nb + n8) = v;
    }
}

// ---------------------------------------------------------------------------
// K4: BN stats from projb (bf16) -> scale/shift. grid 256 (1 block/channel).
// ---------------------------------------------------------------------------
__global__ __launch_bounds__(256) void bn_stats_k(
    const unsigned short* __restrict__ projb, const float* __restrict__ gamma,
    const float* __restrict__ beta, float* __restrict__ stats)
{
    const int c = blockIdx.x;
    const int tid = threadIdx.x;
    float s = 0.f, s2 = 0.f;
    for (int b = 0; b < BB; ++b) {
        const unsigned short* p = projb + ((size_t)(b * CCH + c)) * NN;
        for (int ch = tid; ch < NN / 8; ch += 256) {
            uint4 v = *(const uint4*)(p + ch * 8);
            const unsigned short* e = (const unsigned short*)&v;
            #pragma unroll
            for (int k = 0; k < 8; ++k) {
                float f = bf2f(e[k]);
                s += f; s2 += f * f;
            }
        }
    }
    __shared__ float rs[256], rs2[256];
    rs[tid] = s; rs2[tid] = s2;
    __syncthreads();
    for (int off = 128; off > 0; off >>= 1) {
        if (tid < off) { rs[tid] += rs[tid + off]; rs2[tid] += rs2[tid + off]; }
        __syncthreads();
    }
    if (tid == 0) {
        const float inv_n = 1.0f / (float)(BB * NN);
        float mean = rs[0] * inv_n;
        float var  = rs2[0] * inv_n - mean * mean;
        float sc = gamma[c] * rsqrtf(var + BN_EPS);
        stats[c] = sc;
        stats[CCH + c] = beta[c] - mean * sc;
    }
}

// ---------------------------------------------------------------------------
// K5: out = scale[c]*projb + shift[c] + x   (projb bf16, 8 elems/thread)
// ---------------------------------------------------------------------------
__global__ __launch_bounds__(256) void bn_apply_k(
    const unsigned short* __restrict__ projb, const float* __restrict__ x,
    const float* __restrict__ stats, float* __restrict__ out)
{
    size_t idx = ((size_t)blockIdx.x * 256 + threadIdx.x) * 8;
    const size_t total = (size_t)BB * CCH * NN;
    if (idx >= total) return;
    int c = (int)((idx / NN) % CCH);
    float sc = stats[c], sh = stats[CCH + c];
    uint4 pv = *(const uint4*)(projb + idx);
    const unsigned short* ps = (const unsigned short*)&pv;
    float4 x0 = *(const float4*)(x + idx);
    float4 x1 = *(const float4*)(x + idx + 4);
    float4 r0, r1;
    r0.x = sc * bf2f(ps[0]) + sh + x0.x;
    r0.y = sc * bf2f(ps[1]) + sh + x0.y;
    r0.z = sc * bf2f(ps[2]) + sh + x0.z;
    r0.w = sc * bf2f(ps[3]) + sh + x0.w;
    r1.x = sc * bf2f(ps[4]) + sh + x1.x;
    r1.y = sc * bf2f(ps[5]) + sh + x1.y;
    r1.z = sc * bf2f(ps[6]) + sh + x1.z;
    r1.w = sc * bf2f(ps[7]) + sh + x1.w;
    *(float4*)(out + idx) = r0;
    *(float4*)(out + idx + 4) = r1;
}

extern "C" void kernel_launch(void* const* d_in, const int* in_sizes, int n_in,
                              void* d_out, int out_size, void* d_ws, size_t ws_size,
                              hipStream_t stream)
{
    const float* x     = (const float*)d_in[0];
    const float* qw    = (const float*)d_in[1];
    const float* kw    = (const float*)d_in[2];
    const float* vw    = (const float*)d_in[3];
    const float* pw    = (const float*)d_in[4];
    const float* pb    = (const float*)d_in[5];
    const float* gamma = (const float*)d_in[6];
    const float* beta  = (const float*)d_in[7];
    float* out = (float*)d_out;

    char* ws = (char*)d_ws;
    // Ao overlays xT (dead after K1); projb overlays Qt (dead after K2).
    unsigned short* xT = (unsigned short*)ws;                       //  9,437,184
    unsigned short* Ao = (unsigned short*)ws;                       //  overlay
    unsigned short* Wb = (unsigned short*)(ws + 9437184);           //    196,608
    unsigned short* Pb = (unsigned short*)(ws + 9633792);           //    131,072
    unsigned short* Qt = (unsigned short*)(ws + 9764864);           //  9,437,184
    unsigned short* Kt = (unsigned short*)(ws + 19202048);          //  2,359,296
    unsigned short* Vn = (unsigned short*)(ws + 21561344);          //  2,359,296
    unsigned short* projb = (unsigned short*)(ws + 9764864);        //  overlay (9.4 MB)
    float* stats = (float*)(ws + 28639232);                         //  2,048

    cvt_w_k<<<640, 256, 0, stream>>>(qw, kw, vw, pw, Wb, Pb);

    dim3 g0(BB, NN / 64, CCH / 64);
    cvt_x_k<<<g0, 256, 0, stream>>>(x, xT);

    dim3 g1(BB, NN / 64, 3);
    qkv_mfma_k<<<g1, 128, 0, stream>>>(Wb, xT, Qt, Kt, Vn);

    dim3 g2(BB, NN / 64, NH);
    attn_k<<<g2, 256, 0, stream>>>(Qt, Kt, Vn, Ao);

    dim3 g3(BB, NN / 64, 2);
    proj_mfma_k<<<g3, 128, 0, stream>>>(Pb, Ao, pb, projb);

    bn_stats_k<<<CCH, 256, 0, stream>>>(projb, gamma, beta, stats);

    int total8 = BB * CCH * NN / 8;
    bn_apply_k<<<(total8 + 255) / 256, 256, 0, stream>>>(projb, x, stats, out);
}

// Round 11
// 200.212 us; speedup vs baseline: 1.1848x; 1.1848x over previous
//
#include <hip/hip_runtime.h>
#include <hip/hip_bf16.h>
#include <math.h>

#define BB 8
#define CCH 256          // channels
#define NN 2304          // H*W
#define NH 4
#define HDIM 64
#define QKV_ROWS 384
#define BN_EPS 1e-5f
#define NTILES 36        // NN / 64
#define HTILES 18        // NTILES / 2 (key-split halves)
#define NPART 288        // BB * NTILES proj blocks contributing per channel
// scale folded into q weights: 1/sqrt(64) * log2(e)  -> attention uses exp2
#define SLOG2E 0.18033688011112042f

typedef short bf16x8 __attribute__((ext_vector_type(8)));
typedef short bf16x4 __attribute__((ext_vector_type(4)));
typedef float f32x4 __attribute__((ext_vector_type(4)));

#if __has_builtin(__builtin_amdgcn_exp2f)
#define EXP2(x) __builtin_amdgcn_exp2f(x)
#else
#define EXP2(x) __expf((x) * 0.6931471805599453f)
#endif

// K=16 bf16 MFMA: A/B = 4 bf16 (2 VGPRs), C/D = 4 f32 (ISA §10).
#define MFMA16(a, b, c) __builtin_amdgcn_mfma_f32_16x16x16bf16_1k(a, b, c, 0, 0, 0)
#define MFMA32(a, b, c) __builtin_amdgcn_mfma_f32_16x16x32_bf16(a, b, c, 0, 0, 0)

__device__ __forceinline__ unsigned bfpair(float a, float b) {
    __hip_bfloat162 h = __float22bfloat162_rn(make_float2(a, b));
    return *(unsigned*)&h;
}
__device__ __forceinline__ unsigned short f2bf(float f) {
    unsigned u = __float_as_uint(f);
    u = (u + 0x7FFFu + ((u >> 16) & 1u)) >> 16;
    return (unsigned short)u;
}
__device__ __forceinline__ bf16x4 pack4(float p0, float p1, float p2, float p3) {
    union { unsigned u[2]; bf16x4 v; } x;
    x.u[0] = bfpair(p0, p1);
    x.u[1] = bfpair(p2, p3);
    return x.v;
}
__device__ __forceinline__ float bf2f(unsigned short s) {
    return __uint_as_float((unsigned)s << 16);
}

// ---------------------------------------------------------------------------
// K0: prep — merged x-transpose/convert + weight convert (one launch).
// blocks [0, 1152): x[b][c][n] fp32 -> xT[b][n][c] bf16 (64x64 tiles)
// blocks [1152, 1792): Wb = concat(qw*SLOG2E, kw, vw) bf16; Pb = pw bf16.
// ---------------------------------------------------------------------------
__global__ __launch_bounds__(256) void prep_k(
    const float* __restrict__ x,
    const float* __restrict__ qw, const float* __restrict__ kw,
    const float* __restrict__ vw, const float* __restrict__ pw,
    unsigned short* __restrict__ xT,
    unsigned short* __restrict__ Wb, unsigned short* __restrict__ Pb)
{
    const int bid = blockIdx.x;
    const int tid = threadIdx.x;
    if (bid < 1152) {
        __shared__ float sX[64][65];
        const int b  = bid / 144;
        const int rem = bid - b * 144;
        const int nb = (rem >> 2) * 64;
        const int cb = (rem & 3) * 64;

        #pragma unroll
        for (int u = 0; u < 4; ++u) {
            int c  = (tid >> 4) + 16 * u;
            int n4 = (tid & 15) * 4;
            float4 v = *(const float4*)(x + ((size_t)(b * CCH + cb + c)) * NN + nb + n4);
            sX[c][n4+0] = v.x; sX[c][n4+1] = v.y; sX[c][n4+2] = v.z; sX[c][n4+3] = v.w;
        }
        __syncthreads();

        const int n  = tid >> 2;
        const int cg = (tid & 3) * 16;
        unsigned vals[8];
        #pragma unroll
        for (int p = 0; p < 8; ++p)
            vals[p] = bfpair(sX[cg + 2*p][n], sX[cg + 2*p + 1][n]);
        unsigned short* dst = xT + ((size_t)(b * NN + nb + n)) * CCH + cb + cg;
        *(uint4*)dst = make_uint4(vals[0], vals[1], vals[2], vals[3]);
        *(uint4*)(dst + 8) = make_uint4(vals[4], vals[5], vals[6], vals[7]);
    } else {
        int idx = (bid - 1152) * 256 + tid;
        if (idx < 98304) {
            int o = idx >> 8, c = idx & 255;
            float v;
            if (o < 256)      v = qw[(size_t)o * CCH + c] * SLOG2E;
            else if (o < 320) v = kw[(size_t)(o - 256) * CCH + c];
            else              v = vw[(size_t)(o - 320) * CCH + c];
            Wb[idx] = f2bf(v);
        } else {
            int j = idx - 98304;
            if (j < 65536) Pb[j] = f2bf(pw[j]);
        }
    }
}

// ---------------------------------------------------------------------------
// K1: qkv MFMA GEMM, K-loop software-pipelined (double-buffered fragments).
// grid (8 b, 36 ntile, 3 otile), 128 thr (2 waves).
//   Qt[b][n][256] (q pre-scaled), Kt[b][n][64], Vn[b][64][n], all bf16.
// ---------------------------------------------------------------------------
__global__ __launch_bounds__(128) void qkv_mfma_k(
    const unsigned short* __restrict__ Wb, const unsigned short* __restrict__ xT,
    unsigned short* __restrict__ Qt, unsigned short* __restrict__ Kt,
    unsigned short* __restrict__ Vn)
{
    __shared__ unsigned short sE[2][64 * 72];
    const int tid = threadIdx.x;
    const int wave = tid >> 6;
    const int lane = tid & 63;
    const int quad = lane >> 4;
    const int l15  = lane & 15;
    const int b  = blockIdx.x;
    const int nb = blockIdx.y * 64;
    const int mb = blockIdx.z * 128 + wave * 64;

    const unsigned short* Ab = Wb + (size_t)(mb + l15) * CCH + quad * 8;
    const unsigned short* Bb = xT + ((size_t)(b * NN + nb + l15)) * CCH + quad * 8;

    f32x4 C[4][4] = {};
    bf16x8 aA[2][4], bB[2][4];
    #pragma unroll
    for (int i = 0; i < 4; ++i) aA[0][i] = *(const bf16x8*)(Ab + (size_t)(16*i) * CCH);
    #pragma unroll
    for (int j = 0; j < 4; ++j) bB[0][j] = *(const bf16x8*)(Bb + (size_t)(16*j) * CCH);

    #pragma unroll
    for (int kk = 0; kk < 8; ++kk) {
        const int cur = kk & 1;
        if (kk < 7) {
            const int k1 = (kk + 1) * 32;
            #pragma unroll
            for (int i = 0; i < 4; ++i) aA[cur^1][i] = *(const bf16x8*)(Ab + (size_t)(16*i) * CCH + k1);
            #pragma unroll
            for (int j = 0; j < 4; ++j) bB[cur^1][j] = *(const bf16x8*)(Bb + (size_t)(16*j) * CCH + k1);
        }
        #pragma unroll
        for (int i = 0; i < 4; ++i)
            #pragma unroll
            for (int j = 0; j < 4; ++j)
                C[i][j] = MFMA32(aA[cur][i], bB[cur][j], C[i][j]);
    }

    unsigned short* sEw = &sE[wave][0];
    if (mb < 320) {
        // Q or K: transpose to [n][o] rows
        #pragma unroll
        for (int i = 0; i < 4; ++i)
            #pragma unroll
            for (int j = 0; j < 4; ++j) {
                unsigned p01 = bfpair(C[i][j][0], C[i][j][1]);
                unsigned p23 = bfpair(C[i][j][2], C[i][j][3]);
                unsigned short* p = sEw + (16*j + l15) * 72 + 16*i + quad*4;
                *(unsigned*)p = p01;
                *(unsigned*)(p + 2) = p23;
            }
        if (mb < 256) {
            #pragma unroll
            for (int it = 0; it < 8; ++it) {
                int flat = lane + 64 * it;
                int row = flat >> 3;
                int o8  = (flat & 7) * 8;
                uint4 v = *(const uint4*)(sEw + row * 72 + o8);
                *(uint4*)(Qt + ((size_t)(b * NN + nb + row)) * CCH + mb + o8) = v;
            }
        } else {
            #pragma unroll
            for (int it = 0; it < 8; ++it) {
                int flat = lane + 64 * it;
                int row = flat >> 3;
                int o8  = (flat & 7) * 8;
                uint4 v = *(const uint4*)(sEw + row * 72 + o8);
                *(uint4*)(Kt + ((size_t)(b * NN + nb + row)) * 64 + o8) = v;
            }
        }
    } else {
        // V: [d][n] rows
        #pragma unroll
        for (int i = 0; i < 4; ++i)
            #pragma unroll
            for (int j = 0; j < 4; ++j) {
                unsigned p01 = bfpair(C[i][j][0], C[i][j][1]);
                unsigned p23 = bfpair(C[i][j][2], C[i][j][3]);
                unsigned short* p = sEw + (16*i + quad*4) * 72 + 16*j + l15;
                p[0]   = (unsigned short)p01;
                p[72]  = (unsigned short)(p01 >> 16);
                p[144] = (unsigned short)p23;
                p[216] = (unsigned short)(p23 >> 16);
            }
        #pragma unroll
        for (int it = 0; it < 8; ++it) {
            int flat = lane + 64 * it;
            int row = flat >> 3;
            int n8  = (flat & 7) * 8;
            uint4 v = *(const uint4*)(sEw + row * 72 + n8);
            *(uint4*)(Vn + ((size_t)(b * 64 + (mb - 320) + row)) * NN + nb + n8) = v;
        }
    }
}

// ---------------------------------------------------------------------------
// K2: MFMA attention — exact round-9 version (79.8 µs verified):
// transposed-S + key-split + register prefetch, pad-72 LDS, (256,4).
// Round-10 lesson: (256,5) forces VGPR<=64 quantization step -> pf[] spills
// to scratch -> +66 MB HBM. Do not raise the occupancy hint here.
// ---------------------------------------------------------------------------
__global__ __launch_bounds__(256, 4) void attn_k(
    const unsigned short* __restrict__ Qt,  // [B][N][256]
    const unsigned short* __restrict__ Kt,  // [B][N][64]
    const unsigned short* __restrict__ Vn,  // [B][64][N]
    unsigned short* __restrict__ Ao)        // [B][N][256]
{
    // 4 tile buffers: Kh0, Vh0, Kh1, Vh1 — each [64 rows][72] bf16
    __shared__ __align__(16) unsigned short sKV[4 * 64 * 72];   // 36864 B

    const int tid   = threadIdx.x;
    const int wave  = tid >> 6;
    const int lane  = tid & 63;
    const int quad  = lane >> 4;
    const int l15   = lane & 15;
    const int qslot = wave & 1;
    const int kh    = wave >> 1;
    const int qoff  = qslot * 32;
    const int b     = blockIdx.x;
    const int nb    = blockIdx.y * 64;
    const int head  = blockIdx.z;

    unsigned short* sKb = sKV + kh * 2 * 4608;
    unsigned short* sVb = sKb + 4608;

    // Q fragments (B-operand for S^T): B[n=query=l15][k=d=quad*8+j]
    bf16x8 bQ[2][2];
    const unsigned short* QtB = Qt + ((size_t)(b * NN + nb + qoff + l15)) * CCH + head * 64 + quad * 8;
    #pragma unroll
    for (int qt = 0; qt < 2; ++qt)
        #pragma unroll
        for (int s = 0; s < 2; ++s)
            bQ[qt][s] = *(const bf16x8*)(QtB + (size_t)(16*qt) * CCH + s * 32);

    // per-thread staging geometry (8 chunks: u>>1 = buffer, key-half = buf>>1)
    // prefetch step 0 into registers
    bf16x8 pf[8];
    #pragma unroll
    for (int u = 0; u < 8; ++u) {
        const int buf   = u >> 1;               // 0:K0 1:V0 2:K1 3:V1
        const int khb   = buf >> 1;
        const int local = (u & 1) * 256 + tid;  // 0..511
        const int row   = local >> 3;
        const int ch8   = (local & 7) * 8;
        const int keys0 = khb * HTILES * 64;
        if ((buf & 1) == 0)
            pf[u] = *(const bf16x8*)(Kt + ((size_t)(b * NN + keys0 + row)) * 64 + ch8);
        else
            pf[u] = *(const bf16x8*)(Vn + ((size_t)(b * 64 + row)) * NN + keys0 + ch8);
    }

    f32x4 O[4][2] = {};          // O^T[d-tile jd][q-tile qt]
    float lacc[2] = {0.f, 0.f};  // per-lane partial denominators (q = l15)

    for (int step = 0; step < HTILES; ++step) {
        __syncthreads();   // all waves done with previous tiles
        #pragma unroll
        for (int u = 0; u < 8; ++u) {
            const int buf   = u >> 1;
            const int local = (u & 1) * 256 + tid;
            const int row   = local >> 3;
            const int ch8   = (local & 7) * 8;
            *(bf16x8*)(sKV + buf * 4608 + row * 72 + ch8) = pf[u];
        }
        __syncthreads();

        // prefetch next step during compute
        if (step + 1 < HTILES) {
            #pragma unroll
            for (int u = 0; u < 8; ++u) {
                const int buf   = u >> 1;
                const int khb   = buf >> 1;
                const int local = (u & 1) * 256 + tid;
                const int row   = local >> 3;
                const int ch8   = (local & 7) * 8;
                const int keys0 = (khb * HTILES + step + 1) * 64;
                if ((buf & 1) == 0)
                    pf[u] = *(const bf16x8*)(Kt + ((size_t)(b * NN + keys0 + row)) * 64 + ch8);
                else
                    pf[u] = *(const bf16x8*)(Vn + ((size_t)(b * 64 + row)) * NN + keys0 + ch8);
            }
        }

        // S^T[key][q]: kt = key subtile, qt = query subtile
        f32x4 C[4][2] = {};
        #pragma unroll
        for (int s = 0; s < 2; ++s)
            #pragma unroll
            for (int kt = 0; kt < 4; ++kt) {
                bf16x8 aK = *(const bf16x8*)(sKb + (16*kt + l15) * 72 + s * 32 + quad * 8);
                C[kt][0] = MFMA32(aK, bQ[0][s], C[kt][0]);
                C[kt][1] = MFMA32(aK, bQ[1][s], C[kt][1]);
            }

        // P^T = exp2(S^T) in regs -> bf16 B-fragments for K=16 MFMA
        bf16x4 bP[4][2];
        #pragma unroll
        for (int kt = 0; kt < 4; ++kt)
            #pragma unroll
            for (int qt = 0; qt < 2; ++qt) {
                float p0 = EXP2(C[kt][qt][0]);
                float p1 = EXP2(C[kt][qt][1]);
                float p2 = EXP2(C[kt][qt][2]);
                float p3 = EXP2(C[kt][qt][3]);
                lacc[qt] += (p0 + p1) + (p2 + p3);
                bP[kt][qt] = pack4(p0, p1, p2, p3);
            }

        // O^T += V . P^T   (A = V[d][key], k = quad*4+j keys)
        #pragma unroll
        for (int jd = 0; jd < 4; ++jd)
            #pragma unroll
            for (int kt = 0; kt < 4; ++kt) {
                bf16x4 aV = *(const bf16x4*)(sVb + (16*jd + l15) * 72 + 16*kt + quad*4);
                O[jd][0] = MFMA16(aV, bP[kt][0], O[jd][0]);
                O[jd][1] = MFMA16(aV, bP[kt][1], O[jd][1]);
            }
    }
    __syncthreads();   // all K/V reads done before scratch overlay

    // merge key halves: kh=1 waves dump O + lacc to LDS scratch (floats)
    float* sc = (float*)sKV;                           // 0..18432 B
    unsigned short* sT = (unsigned short*)sKV + 9216;  // 18432..27648 B, [64][72]
    if (kh == 1) {
        const int base = qslot * 2304 + lane * 36;
        #pragma unroll
        for (int jd = 0; jd < 4; ++jd)
            #pragma unroll
            for (int qt = 0; qt < 2; ++qt)
                *(f32x4*)(sc + base + jd * 8 + qt * 4) = O[jd][qt];
        sc[base + 32] = lacc[0];
        sc[base + 33] = lacc[1];
    }
    __syncthreads();
    if (kh == 0) {
        const int base = qslot * 2304 + lane * 36;
        #pragma unroll
        for (int jd = 0; jd < 4; ++jd)
            #pragma unroll
            for (int qt = 0; qt < 2; ++qt)
                O[jd][qt] += *(const f32x4*)(sc + base + jd * 8 + qt * 4);
        lacc[0] += sc[base + 32];
        lacc[1] += sc[base + 33];

        float rinv[2];
        #pragma unroll
        for (int qt = 0; qt < 2; ++qt) {
            float s = lacc[qt];
            s += __shfl_xor(s, 16);
            s += __shfl_xor(s, 32);
            rinv[qt] = 1.0f / s;
        }
        // sT[n_local][d]: n = qoff + 16qt + l15, d = 16jd + quad*4 + r
        #pragma unroll
        for (int qt = 0; qt < 2; ++qt)
            #pragma unroll
            for (int jd = 0; jd < 4; ++jd) {
                unsigned lo = bfpair(O[jd][qt][0] * rinv[qt], O[jd][qt][1] * rinv[qt]);
                unsigned hi = bfpair(O[jd][qt][2] * rinv[qt], O[jd][qt][3] * rinv[qt]);
                *(uint2*)(sT + (qoff + 16*qt + l15) * 72 + 16*jd + quad*4) = make_uint2(lo, hi);
            }
    }
    __syncthreads();

    // coalesced writeout: 64 rows x 64 channels bf16 = 512 uint4 chunks
    #pragma unroll
    for (int it = 0; it < 2; ++it) {
        int flat = tid + 256 * it;          // 0..511
        int row = flat >> 3;
        int c8  = (flat & 7) * 8;
        uint4 v = *(const uint4*)(sT + row * 72 + c8);
        *(uint4*)(Ao + ((size_t)(b * NN + nb + row)) * CCH + head * 64 + c8) = v;
    }
}

// ---------------------------------------------------------------------------
// K3: proj MFMA GEMM, pipelined, + per-block BN partials (no atomics).
// projb[b][c][n] (bf16) = sum_o Pb[c][o]*Ao[b][n][o]+pb[c]
// psum/psq[ch][b*36+nt] = partial sum / sumsq over this block's 64 n.
// grid (8 b, 36 ntile, 2 ctile), 128 thr (2 waves).
// ---------------------------------------------------------------------------
__global__ __launch_bounds__(128) void proj_mfma_k(
    const unsigned short* __restrict__ Pb, const unsigned short* __restrict__ Ao,
    const float* __restrict__ pb, unsigned short* __restrict__ projb,
    float* __restrict__ psum, float* __restrict__ psq)
{
    __shared__ unsigned short sE[2][64 * 72];
    const int tid = threadIdx.x;
    const int wave = tid >> 6;
    const int lane = tid & 63;
    const int quad = lane >> 4;
    const int l15  = lane & 15;
    const int b  = blockIdx.x;
    const int nb = blockIdx.y * 64;
    const int mb = blockIdx.z * 128 + wave * 64;
    const int part = b * NTILES + blockIdx.y;   // 0..287

    const unsigned short* Ab = Pb + (size_t)(mb + l15) * CCH + quad * 8;
    const unsigned short* Bb = Ao + ((size_t)(b * NN + nb + l15)) * CCH + quad * 8;

    f32x4 C[4][4] = {};
    bf16x8 aA[2][4], bB[2][4];
    #pragma unroll
    for (int i = 0; i < 4; ++i) aA[0][i] = *(const bf16x8*)(Ab + (size_t)(16*i) * CCH);
    #pragma unroll
    for (int j = 0; j < 4; ++j) bB[0][j] = *(const bf16x8*)(Bb + (size_t)(16*j) * CCH);

    #pragma unroll
    for (int kk = 0; kk < 8; ++kk) {
        const int cur = kk & 1;
        if (kk < 7) {
            const int k1 = (kk + 1) * 32;
            #pragma unroll
            for (int i = 0; i < 4; ++i) aA[cur^1][i] = *(const bf16x8*)(Ab + (size_t)(16*i) * CCH + k1);
            #pragma unroll
            for (int j = 0; j < 4; ++j) bB[cur^1][j] = *(const bf16x8*)(Bb + (size_t)(16*j) * CCH + k1);
        }
        #pragma unroll
        for (int i = 0; i < 4; ++i)
            #pragma unroll
            for (int j = 0; j < 4; ++j)
                C[i][j] = MFMA32(aA[cur][i], bB[cur][j], C[i][j]);
    }

    unsigned short* sEw = &sE[wave][0];
    #pragma unroll
    for (int i = 0; i < 4; ++i) {
        #pragma unroll
        for (int r = 0; r < 4; ++r) {
            const int ch = mb + 16*i + quad*4 + r;
            const float bias = pb[ch];
            float v0 = C[i][0][r] + bias, v1 = C[i][1][r] + bias;
            float v2 = C[i][2][r] + bias, v3 = C[i][3][r] + bias;
            C[i][0][r] = v0; C[i][1][r] = v1; C[i][2][r] = v2; C[i][3][r] = v3;
            // partial stats over this block's 64 n for channel ch
            float rs = (v0 + v1) + (v2 + v3);
            float rq = (v0*v0 + v1*v1) + (v2*v2 + v3*v3);
            rs += __shfl_xor(rs, 1); rq += __shfl_xor(rq, 1);
            rs += __shfl_xor(rs, 2); rq += __shfl_xor(rq, 2);
            rs += __shfl_xor(rs, 4); rq += __shfl_xor(rq, 4);
            rs += __shfl_xor(rs, 8); rq += __shfl_xor(rq, 8);
            if (l15 == 0) {
                psum[(size_t)ch * NPART + part] = rs;
                psq [(size_t)ch * NPART + part] = rq;
            }
        }
    }

    // bf16 output via LDS transpose: rows = c_local, cols = n
    #pragma unroll
    for (int i = 0; i < 4; ++i)
        #pragma unroll
        for (int j = 0; j < 4; ++j) {
            unsigned p01 = bfpair(C[i][j][0], C[i][j][1]);
            unsigned p23 = bfpair(C[i][j][2], C[i][j][3]);
            unsigned short* p = sEw + (16*i + quad*4) * 72 + 16*j + l15;
            p[0]   = (unsigned short)p01;
            p[72]  = (unsigned short)(p01 >> 16);
            p[144] = (unsigned short)p23;
            p[216] = (unsigned short)(p23 >> 16);
        }
    #pragma unroll
    for (int it = 0; it < 8; ++it) {
        int flat = lane + 64 * it;
        int row = flat >> 3;                // c local
        int n8  = (flat & 7) * 8;
        uint4 v = *(const uint4*)(sEw + row * 72 + n8);
        *(uint4*)(projb + ((size_t)(b * CCH + mb + row)) * NN + nb + n8) = v;
    }
}

// ---------------------------------------------------------------------------
// K4: finalize BN from partials. 256 blocks x 64 thr: block = channel,
// 64 threads reduce 288 partials (x2) via wave shuffle.
// ---------------------------------------------------------------------------
__global__ __launch_bounds__(64) void bn_finalize_k(
    const float* __restrict__ psum, const float* __restrict__ psq,
    const float* __restrict__ gamma, const float* __restrict__ beta,
    float* __restrict__ stats)
{
    const int c = blockIdx.x;
    const int lane = threadIdx.x;
    float s = 0.f, q = 0.f;
    for (int k = lane; k < NPART; k += 64) {
        s += psum[(size_t)c * NPART + k];
        q += psq [(size_t)c * NPART + k];
    }
    #pragma unroll
    for (int off = 1; off < 64; off <<= 1) {
        s += __shfl_xor(s, off);
        q += __shfl_xor(q, off);
    }
    if (lane == 0) {
        const float inv_n = 1.0f / (float)(BB * NN);
        float mean = s * inv_n;
        float var  = q * inv_n - mean * mean;
        float sc = gamma[c] * rsqrtf(var + BN_EPS);
        stats[c] = sc;
        stats[CCH + c] = beta[c] - mean * sc;
    }
}

// ---------------------------------------------------------------------------
// K5: out = scale[c]*projb + shift[c] + x   (projb bf16, 8 elems/thread)
// ---------------------------------------------------------------------------
__global__ __launch_bounds__(256) void bn_apply_k(
    const unsigned short* __restrict__ projb, const float* __restrict__ x,
    const float* __restrict__ stats, float* __restrict__ out)
{
    size_t idx = ((size_t)blockIdx.x * 256 + threadIdx.x) * 8;
    const size_t total = (size_t)BB * CCH * NN;
    if (idx >= total) return;
    int c = (int)((idx / NN) % CCH);
    float sc = stats[c], sh = stats[CCH + c];
    uint4 pv = *(const uint4*)(projb + idx);
    const unsigned short* ps = (const unsigned short*)&pv;
    float4 x0 = *(const float4*)(x + idx);
    float4 x1 = *(const float4*)(x + idx + 4);
    float4 r0, r1;
    r0.x = sc * bf2f(ps[0]) + sh + x0.x;
    r0.y = sc * bf2f(ps[1]) + sh + x0.y;
    r0.z = sc * bf2f(ps[2]) + sh + x0.z;
    r0.w = sc * bf2f(ps[3]) + sh + x0.w;
    r1.x = sc * bf2f(ps[4]) + sh + x1.x;
    r1.y = sc * bf2f(ps[5]) + sh + x1.y;
    r1.z = sc * bf2f(ps[6]) + sh + x1.z;
    r1.w = sc * bf2f(ps[7]) + sh + x1.w;
    *(float4*)(out + idx) = r0;
    *(float4*)(out + idx + 4) = r1;
}

extern "C" void kernel_launch(void* const* d_in, const int* in_sizes, int n_in,
                              void* d_out, int out_size, void* d_ws, size_t ws_size,
                              hipStream_t stream)
{
    const float* x     = (const float*)d_in[0];
    const float* qw    = (const float*)d_in[1];
    const float* kw    = (const float*)d_in[2];
    const float* vw    = (const float*)d_in[3];
    const float* pw    = (const float*)d_in[4];
    const float* pb    = (const float*)d_in[5];
    const float* gamma = (const float*)d_in[6];
    const float* beta  = (const float*)d_in[7];
    float* out = (float*)d_out;

    char* ws = (char*)d_ws;
    // Ao overlays xT (dead after K1); projb overlays Qt (dead after K2).
    unsigned short* xT = (unsigned short*)ws;                       //  9,437,184
    unsigned short* Ao = (unsigned short*)ws;                       //  overlay
    unsigned short* Wb = (unsigned short*)(ws + 9437184);           //    196,608
    unsigned short* Pb = (unsigned short*)(ws + 9633792);           //    131,072
    unsigned short* Qt = (unsigned short*)(ws + 9764864);           //  9,437,184
    unsigned short* Kt = (unsigned short*)(ws + 19202048);          //  2,359,296
    unsigned short* Vn = (unsigned short*)(ws + 21561344);          //  2,359,296
    unsigned short* projb = (unsigned short*)(ws + 9764864);        //  overlay (9.4 MB)
    float* stats = (float*)(ws + 28639232);                         //  2,048
    float* psum  = (float*)(ws + 28641280);                         //  294,912
    float* psq   = (float*)(ws + 28936192);                         //  294,912

    prep_k<<<1792, 256, 0, stream>>>(x, qw, kw, vw, pw, xT, Wb, Pb);

    dim3 g1(BB, NN / 64, 3);
    qkv_mfma_k<<<g1, 128, 0, stream>>>(Wb, xT, Qt, Kt, Vn);

    dim3 g2(BB, NN / 64, NH);
    attn_k<<<g2, 256, 0, stream>>>(Qt, Kt, Vn, Ao);

    dim3 g3(BB, NN / 64, 2);
    proj_mfma_k<<<g3, 128, 0, stream>>>(Pb, Ao, pb, projb, psum, psq);

    bn_finalize_k<<<CCH, 64, 0, stream>>>(psum, psq, gamma, beta, stats);

    int total8 = BB * CCH * NN / 8;
    bn_apply_k<<<(total8 + 255) / 256, 256, 0, stream>>>(projb, x, stats, out);
}